// Round 1
// baseline (1488.963 us; speedup 1.0000x reference)
//
#include <hip/hip_runtime.h>
#include <hip/hip_bf16.h>

typedef __attribute__((ext_vector_type(4))) float f32x4;
typedef __attribute__((ext_vector_type(8))) short bf16x8;

#define NDIM 6
#define IN_DIM 256
#define OUT_DIM 256
#define KW 780          // W inner dim (256*3 + 6*2)
#define NR 262          // node_rep row (256+6)
#define NRP 264         // padded node_rep row for 16B-aligned chunks
#define K2 832          // padded GEMM K = 13*64
#define BM 128
#define BK 64
#define NTILES 13

__device__ __forceinline__ short f2bf(float f) {
  return __builtin_bit_cast(short, __float2bfloat16(f));
}

__device__ __forceinline__ void gload_lds16(void* lds, const void* g) {
  __builtin_amdgcn_global_load_lds(
      (const __attribute__((address_space(1))) unsigned int*)g,
      (__attribute__((address_space(3))) unsigned int*)lds, 16, 0, 0);
}

// ---------------- aggregation: num[col] += ea*m, den[col] += m ----------------
__global__ void agg_kernel(const int* __restrict__ ei, const float* __restrict__ ea,
                           const float* __restrict__ mask, float* __restrict__ num,
                           float* __restrict__ den, int E) {
  int e = blockIdx.x * 4 + (threadIdx.x >> 6);
  if (e >= E) return;
  int lane = threadIdx.x & 63;
  int col = ei[(long)E + e];
  float m = mask[e];
  f32x4 v = ((const f32x4*)ea)[(long)e * 64 + lane];
  float* dst = num + (long)col * IN_DIM + lane * 4;
  unsafeAtomicAdd(dst + 0, v.x * m);
  unsafeAtomicAdd(dst + 1, v.y * m);
  unsafeAtomicAdd(dst + 2, v.z * m);
  unsafeAtomicAdd(dst + 3, v.w * m);
  if (lane == 0) unsafeAtomicAdd(den + col, m);
}

// ---------------- node_rep = [num/(den+1), x]; also bf16 copy ----------------
__global__ void noderep_kernel(const float* __restrict__ num, const float* __restrict__ den,
                               const float* __restrict__ x, float* __restrict__ outN,
                               short* __restrict__ nrepb, int N) {
  int n = blockIdx.x;
  int t = threadIdx.x;
  float inv = 1.0f / (den[n] + 1.0f);
  float v = num[(long)n * IN_DIM + t] * inv;
  outN[(long)n * NR + t] = v;
  nrepb[(long)n * NRP + t] = f2bf(v);
  if (t < NDIM) {
    float xv = x[(long)n * NDIM + t];
    outN[(long)n * NR + IN_DIM + t] = xv;
    nrepb[(long)n * NRP + IN_DIM + t] = f2bf(xv);
  } else if (t < 8) {
    nrepb[(long)n * NRP + IN_DIM + t] = 0;  // row pad -> 0
  }
}

// ---------------- W -> bf16, transposed to padded K layout [256][832] --------
// k' order: [ea(256) | nrep_row(264) | nrep_col(264) | pad(48)]
__global__ void wprep_kernel(const float* __restrict__ W, short* __restrict__ Wtb) {
  int idx = blockIdx.x * 256 + threadIdx.x;
  if (idx >= OUT_DIM * K2) return;
  int n = idx / K2, k = idx % K2;
  float v = 0.0f;
  if (k < 256) {
    v = W[(long)n * KW + 524 + k];           // ea part: original j = 524+k
  } else if (k < 520) {
    int kk = k - 256; if (kk < NR) v = W[(long)n * KW + kk];          // nrep[row]
  } else if (k < 784) {
    int kk = k - 520; if (kk < NR) v = W[(long)n * KW + NR + kk];     // nrep[col]
  }
  Wtb[idx] = f2bf(v);
}

// ---------------- fused gather + GEMM: out = [nr[row],nr[col],ea] @ W^T + b --
__global__ __launch_bounds__(512) void gemm_kernel(
    const int* __restrict__ ei, const float* __restrict__ ea,
    const short* __restrict__ nrepb, const short* __restrict__ Wtb,
    const float* __restrict__ bias, const short* __restrict__ zerobuf,
    float* __restrict__ outE, int E) {
  __shared__ short Abuf[2][BM * BK];

  const int tid = threadIdx.x;
  const int wave = tid >> 6, lane = tid & 63;
  const long e0 = (long)blockIdx.x * BM;
  const int wm = wave >> 2, wn = wave & 3;      // 2M x 4N wave grid
  const int mbase = wm * 64, nbase = wn * 64;

  // --- staging precompute for global_load_lds path (tiles >= 4) ---
  // wave instr i covers rows [16*wave + 8i, +8); lane -> row 16w+8i+(lane>>3), chunk-pos lane&7
  int srow[2], ridx[2], cidx[2];
  const int scp = lane & 7;
  srow[0] = 16 * wave + (lane >> 3);
  srow[1] = srow[0] + 8;
#pragma unroll
  for (int i = 0; i < 2; ++i) {
    long ec = e0 + srow[i]; if (ec >= E) ec = E - 1;
    ridx[i] = ei[ec];
    cidx[i] = ei[(long)E + ec];
  }

  f32x4 acc[4][4];
#pragma unroll
  for (int mf = 0; mf < 4; ++mf)
#pragma unroll
    for (int nf = 0; nf < 4; ++nf) acc[mf][nf] = (f32x4)0.0f;

  // --- staging lambdas ---
  auto stage_ea = [&](int t, int buf) {  // tiles 0..3: ea f32 -> bf16, swizzled ds_write
    const int k0 = t * BK;
#pragma unroll
    for (int i = 0; i < 2; ++i) {
      int g = tid + i * 512;
      int row = g >> 3, cp = g & 7;
      int c = cp ^ (row & 7);
      int k = k0 + 8 * c;
      long e = e0 + row; if (e >= E) e = E - 1;
      const f32x4* s = (const f32x4*)(ea + (e * IN_DIM + k));
      f32x4 v0 = s[0], v1 = s[1];
      bf16x8 p;
      p[0] = f2bf(v0.x); p[1] = f2bf(v0.y); p[2] = f2bf(v0.z); p[3] = f2bf(v0.w);
      p[4] = f2bf(v1.x); p[5] = f2bf(v1.y); p[6] = f2bf(v1.z); p[7] = f2bf(v1.w);
      *(bf16x8*)&Abuf[buf][row * BK + cp * 8] = p;
    }
  };

  auto stage_nr = [&](int t, int buf) {  // tiles 4..12: global_load_lds, pre-swizzled src
    const int k0 = t * BK;
#pragma unroll
    for (int i = 0; i < 2; ++i) {
      int row = srow[i];
      int c = scp ^ (row & 7);
      int k = k0 + 8 * c;
      const short* src;
      if (k < 520)      src = nrepb + (long)ridx[i] * NRP + (k - 256);
      else if (k < 784) src = nrepb + (long)cidx[i] * NRP + (k - 520);
      else              src = zerobuf;
      gload_lds16(&Abuf[buf][(16 * wave + i * 8) * BK], src);
    }
  };

  auto compute = [&](int t, int buf) {
#pragma unroll
    for (int s2 = 0; s2 < 2; ++s2) {
      bf16x8 a[4], bv[4];
      int cl = s2 * 4 + (lane >> 4);
#pragma unroll
      for (int mf = 0; mf < 4; ++mf) {
        int m = mbase + 16 * mf + (lane & 15);
        a[mf] = *(const bf16x8*)&Abuf[buf][m * BK + ((cl ^ (m & 7)) * 8)];
      }
      int kg = t * BK + s2 * 32 + (lane >> 4) * 8;
#pragma unroll
      for (int nf = 0; nf < 4; ++nf) {
        int n = nbase + 16 * nf + (lane & 15);
        bv[nf] = *(const bf16x8*)&Wtb[n * K2 + kg];
      }
#pragma unroll
      for (int mf = 0; mf < 4; ++mf)
#pragma unroll
        for (int nf = 0; nf < 4; ++nf)
          acc[mf][nf] = __builtin_amdgcn_mfma_f32_16x16x32_bf16(a[mf], bv[nf], acc[mf][nf], 0, 0, 0);
    }
  };

  // --- main loop: stage(t+1) overlaps compute(t); dbuf; 1 barrier/tile ---
  stage_ea(0, 0);
  __syncthreads();
  for (int t = 0; t < NTILES; ++t) {
    int buf = t & 1;
    if (t + 1 < NTILES) {
      if (t + 1 < 4) stage_ea(t + 1, buf ^ 1);
      else           stage_nr(t + 1, buf ^ 1);
    }
    compute(t, buf);
    __syncthreads();
  }

  // --- epilogue: C layout col=lane&15, row=(lane>>4)*4+reg (m89-verified) ---
  float bvals[4];
#pragma unroll
  for (int nf = 0; nf < 4; ++nf) bvals[nf] = bias[nbase + 16 * nf + (lane & 15)];
#pragma unroll
  for (int mf = 0; mf < 4; ++mf) {
#pragma unroll
    for (int nf = 0; nf < 4; ++nf) {
#pragma unroll
      for (int q = 0; q < 4; ++q) {
        long e = e0 + mbase + 16 * mf + (lane >> 4) * 4 + q;
        if (e < E)
          outE[e * OUT_DIM + nbase + 16 * nf + (lane & 15)] = acc[mf][nf][q] + bvals[nf];
      }
    }
  }
}

extern "C" void kernel_launch(void* const* d_in, const int* in_sizes, int n_in,
                              void* d_out, int out_size, void* d_ws, size_t ws_size,
                              hipStream_t stream) {
  const float* x    = (const float*)d_in[0];
  const int*   ei   = (const int*)d_in[2];
  const float* ea   = (const float*)d_in[3];
  const float* mask = (const float*)d_in[4];
  const float* W    = (const float*)d_in[5];
  const float* b    = (const float*)d_in[6];
  const int E = in_sizes[4];
  const int N = in_sizes[0] / NDIM;

  // ws layout (all 16B aligned)
  float* num     = (float*)d_ws;                       // N*256 f32
  float* den     = num + (long)N * IN_DIM;             // N f32
  float* zerobuf = den + N;                            // 64 f32 of zeros
  short* nrepb   = (short*)(zerobuf + 64);             // N*264 bf16
  short* Wtb     = nrepb + (long)N * NRP;              // 256*832 bf16

  float* outN = (float*)d_out;
  float* outE = outN + (long)N * NR;

  size_t zbytes = ((size_t)N * IN_DIM + N + 64) * sizeof(float);
  hipMemsetAsync(d_ws, 0, zbytes, stream);

  agg_kernel<<<(E + 3) / 4, 256, 0, stream>>>(ei, ea, mask, num, den, E);
  noderep_kernel<<<N, 256, 0, stream>>>(num, den, x, outN, nrepb, N);
  wprep_kernel<<<(OUT_DIM * K2 + 255) / 256, 256, 0, stream>>>(W, Wtb);
  gemm_kernel<<<(E + BM - 1) / BM, 512, 0, stream>>>(ei, ea, nrepb, Wtb, b,
                                                     (const short*)zerobuf, outE, E);
}

// Round 2
// 596.836 us; speedup vs baseline: 2.4948x; 2.4948x over previous
//
#include <hip/hip_runtime.h>
#include <hip/hip_bf16.h>
#include <stdint.h>

typedef __attribute__((ext_vector_type(4))) float f32x4;
typedef __attribute__((ext_vector_type(8))) short bf16x8;

#define NDIM 6
#define IN_DIM 256
#define OUT_DIM 256
#define KW 780          // W inner dim (256*3 + 6*2)
#define NR 262          // node_rep row (256+6)
#define NRP 264         // padded node_rep row for 16B-aligned chunks
#define K2 832          // padded GEMM K = 13*64
#define BM 128
#define BK 64
#define NTILES 13
#define SCAN_T 1024

__device__ __forceinline__ short f2bf(float f) {
  return __builtin_bit_cast(short, __float2bfloat16(f));
}

__device__ __forceinline__ void gload_lds16(void* lds, const void* g) {
  __builtin_amdgcn_global_load_lds(
      (const __attribute__((address_space(1))) unsigned int*)g,
      (__attribute__((address_space(3))) unsigned int*)lds, 16, 0, 0);
}

// ---------------- CSR build: histogram of destination nodes ----------------
__global__ void hist_kernel(const int* __restrict__ ei, int* __restrict__ counts, int E) {
  int e = blockIdx.x * 256 + threadIdx.x;
  if (e < E) atomicAdd(&counts[ei[(long)E + e]], 1);
}

// exclusive prefix sum over counts (single block, Hillis-Steele on partials)
__global__ __launch_bounds__(SCAN_T) void scan_kernel(const int* __restrict__ counts,
                                                      int* __restrict__ offsets, int N) {
  __shared__ int part[SCAN_T];
  int t = threadIdx.x;
  int chunk = (N + SCAN_T - 1) / SCAN_T;
  int begin = t * chunk;
  int s = 0;
  for (int i = 0; i < chunk; ++i) {
    int idx = begin + i;
    if (idx < N) s += counts[idx];
  }
  part[t] = s;
  __syncthreads();
  for (int d = 1; d < SCAN_T; d <<= 1) {
    int v = (t >= d) ? part[t - d] : 0;
    __syncthreads();
    part[t] += v;
    __syncthreads();
  }
  int run = (t == 0) ? 0 : part[t - 1];
  for (int i = 0; i < chunk; ++i) {
    int idx = begin + i;
    if (idx < N) { offsets[idx] = run; run += counts[idx]; }
  }
}

__global__ void scatter_kernel(const int* __restrict__ ei, const int* __restrict__ offsets,
                               int* __restrict__ cursor, int* __restrict__ csr, int E) {
  int e = blockIdx.x * 256 + threadIdx.x;
  if (e >= E) return;
  int col = ei[(long)E + e];
  int pos = atomicAdd(&cursor[col], 1);
  csr[offsets[col] + pos] = e;
}

// ------- gather-reduce per node + node_rep emit (f32 out + bf16 copy) -------
// one wave per node; lane owns 4 channels (f32x4)
__global__ __launch_bounds__(256) void reduce_kernel(
    const int* __restrict__ csr, const int* __restrict__ offsets,
    const int* __restrict__ counts, const float* __restrict__ ea,
    const float* __restrict__ mask, const float* __restrict__ x,
    float* __restrict__ outN, short* __restrict__ nrepb, int N) {
  int n = blockIdx.x * 4 + (threadIdx.x >> 6);
  if (n >= N) return;
  int lane = threadIdx.x & 63;
  int s = offsets[n], cnt = counts[n];
  f32x4 sum = (f32x4)0.0f;
  float den = 0.0f;
  for (int i = 0; i < cnt; ++i) {
    int e = csr[s + i];
    float m = mask[e];
    den += m;
    f32x4 v = ((const f32x4*)ea)[(long)e * 64 + lane];
    sum.x += v.x * m; sum.y += v.y * m; sum.z += v.z * m; sum.w += v.w * m;
  }
  float inv = 1.0f / (den + 1.0f);
  sum.x *= inv; sum.y *= inv; sum.z *= inv; sum.w *= inv;
  float* po = outN + (long)n * NR + lane * 4;
  po[0] = sum.x; po[1] = sum.y; po[2] = sum.z; po[3] = sum.w;
  short4 pb;
  pb.x = f2bf(sum.x); pb.y = f2bf(sum.y); pb.z = f2bf(sum.z); pb.w = f2bf(sum.w);
  *(short4*)(nrepb + (long)n * NRP + lane * 4) = pb;
  if (lane < NDIM) {
    float xv = x[(long)n * NDIM + lane];
    outN[(long)n * NR + IN_DIM + lane] = xv;
    nrepb[(long)n * NRP + IN_DIM + lane] = f2bf(xv);
  } else if (lane < 8) {
    nrepb[(long)n * NRP + IN_DIM + lane] = 0;  // row pad -> 0
  }
}

// ---------------- W -> bf16, transposed to padded K layout [256][832] --------
// k' order: [ea(256) | nrep_row(264) | nrep_col(264) | pad(48)]
__global__ void wprep_kernel(const float* __restrict__ W, short* __restrict__ Wtb) {
  int idx = blockIdx.x * 256 + threadIdx.x;
  if (idx >= OUT_DIM * K2) return;
  int n = idx / K2, k = idx % K2;
  float v = 0.0f;
  if (k < 256) {
    v = W[(long)n * KW + 524 + k];           // ea part: original j = 524+k
  } else if (k < 520) {
    int kk = k - 256; if (kk < NR) v = W[(long)n * KW + kk];          // nrep[row]
  } else if (k < 784) {
    int kk = k - 520; if (kk < NR) v = W[(long)n * KW + NR + kk];     // nrep[col]
  }
  Wtb[idx] = f2bf(v);
}

// ---------------- fused gather + GEMM: out = [nr[row],nr[col],ea] @ W^T + b --
__global__ __launch_bounds__(512) void gemm_kernel(
    const int* __restrict__ ei, const float* __restrict__ ea,
    const short* __restrict__ nrepb, const short* __restrict__ Wtb,
    const float* __restrict__ bias, const short* __restrict__ zerobuf,
    float* __restrict__ outE, int E) {
  __shared__ short Abuf[2][BM * BK];

  const int tid = threadIdx.x;
  const int wave = tid >> 6, lane = tid & 63;
  const long e0 = (long)blockIdx.x * BM;
  const int wm = wave >> 2, wn = wave & 3;      // 2M x 4N wave grid
  const int mbase = wm * 64, nbase = wn * 64;

  // --- staging precompute for global_load_lds path (tiles >= 4) ---
  int srow[2], ridx[2], cidx[2];
  const int scp = lane & 7;
  srow[0] = 16 * wave + (lane >> 3);
  srow[1] = srow[0] + 8;
#pragma unroll
  for (int i = 0; i < 2; ++i) {
    long ec = e0 + srow[i]; if (ec >= E) ec = E - 1;
    ridx[i] = ei[ec];
    cidx[i] = ei[(long)E + ec];
  }

  f32x4 acc[4][4];
#pragma unroll
  for (int mf = 0; mf < 4; ++mf)
#pragma unroll
    for (int nf = 0; nf < 4; ++nf) acc[mf][nf] = (f32x4)0.0f;

  auto stage_ea = [&](int t, int buf) {  // tiles 0..3: ea f32 -> bf16, swizzled ds_write
    const int k0 = t * BK;
#pragma unroll
    for (int i = 0; i < 2; ++i) {
      int g = tid + i * 512;
      int row = g >> 3, cp = g & 7;
      int c = cp ^ (row & 7);
      int k = k0 + 8 * c;
      long e = e0 + row; if (e >= E) e = E - 1;
      const f32x4* s = (const f32x4*)(ea + (e * IN_DIM + k));
      f32x4 v0 = s[0], v1 = s[1];
      bf16x8 p;
      p[0] = f2bf(v0.x); p[1] = f2bf(v0.y); p[2] = f2bf(v0.z); p[3] = f2bf(v0.w);
      p[4] = f2bf(v1.x); p[5] = f2bf(v1.y); p[6] = f2bf(v1.z); p[7] = f2bf(v1.w);
      *(bf16x8*)&Abuf[buf][row * BK + cp * 8] = p;
    }
  };

  auto stage_nr = [&](int t, int buf) {  // tiles 4..12: global_load_lds, pre-swizzled src
    const int k0 = t * BK;
#pragma unroll
    for (int i = 0; i < 2; ++i) {
      int row = srow[i];
      int c = scp ^ (row & 7);
      int k = k0 + 8 * c;
      const short* src;
      if (k < 520)      src = nrepb + (long)ridx[i] * NRP + (k - 256);
      else if (k < 784) src = nrepb + (long)cidx[i] * NRP + (k - 520);
      else              src = zerobuf;
      gload_lds16(&Abuf[buf][(16 * wave + i * 8) * BK], src);
    }
  };

  auto compute = [&](int t, int buf) {
#pragma unroll
    for (int s2 = 0; s2 < 2; ++s2) {
      bf16x8 a[4], bv[4];
      int cl = s2 * 4 + (lane >> 4);
#pragma unroll
      for (int mf = 0; mf < 4; ++mf) {
        int m = mbase + 16 * mf + (lane & 15);
        a[mf] = *(const bf16x8*)&Abuf[buf][m * BK + ((cl ^ (m & 7)) * 8)];
      }
      int kg = t * BK + s2 * 32 + (lane >> 4) * 8;
#pragma unroll
      for (int nf = 0; nf < 4; ++nf) {
        int n = nbase + 16 * nf + (lane & 15);
        bv[nf] = *(const bf16x8*)&Wtb[n * K2 + kg];
      }
#pragma unroll
      for (int mf = 0; mf < 4; ++mf)
#pragma unroll
        for (int nf = 0; nf < 4; ++nf)
          acc[mf][nf] = __builtin_amdgcn_mfma_f32_16x16x32_bf16(a[mf], bv[nf], acc[mf][nf], 0, 0, 0);
    }
  };

  stage_ea(0, 0);
  __syncthreads();
  for (int t = 0; t < NTILES; ++t) {
    int buf = t & 1;
    if (t + 1 < NTILES) {
      if (t + 1 < 4) stage_ea(t + 1, buf ^ 1);
      else           stage_nr(t + 1, buf ^ 1);
    }
    compute(t, buf);
    __syncthreads();
  }

  float bvals[4];
#pragma unroll
  for (int nf = 0; nf < 4; ++nf) bvals[nf] = bias[nbase + 16 * nf + (lane & 15)];
#pragma unroll
  for (int mf = 0; mf < 4; ++mf) {
#pragma unroll
    for (int nf = 0; nf < 4; ++nf) {
#pragma unroll
      for (int q = 0; q < 4; ++q) {
        long e = e0 + mbase + 16 * mf + (lane >> 4) * 4 + q;
        if (e < E)
          outE[e * OUT_DIM + nbase + 16 * nf + (lane & 15)] = acc[mf][nf][q] + bvals[nf];
      }
    }
  }
}

extern "C" void kernel_launch(void* const* d_in, const int* in_sizes, int n_in,
                              void* d_out, int out_size, void* d_ws, size_t ws_size,
                              hipStream_t stream) {
  const float* x    = (const float*)d_in[0];
  const int*   ei   = (const int*)d_in[2];
  const float* ea   = (const float*)d_in[3];
  const float* mask = (const float*)d_in[4];
  const float* W    = (const float*)d_in[5];
  const float* b    = (const float*)d_in[6];
  const int E = in_sizes[4];
  const int N = in_sizes[0] / NDIM;

  // ws layout
  char* p = (char*)d_ws;
  int* counts  = (int*)p; p += (long)N * 4;
  int* cursor  = (int*)p; p += (long)N * 4;
  int* offsets = (int*)p; p += (long)(N + 1) * 4;
  int* csr     = (int*)p; p += (long)E * 4;
  p = (char*)(((uintptr_t)p + 15) & ~(uintptr_t)15);
  float* zerobuf = (float*)p; p += 64 * 4;
  short* nrepb   = (short*)p; p += (long)N * NRP * 2;
  short* Wtb     = (short*)p;

  float* outN = (float*)d_out;
  float* outE = outN + (long)N * NR;

  hipMemsetAsync(counts, 0, (size_t)2 * N * 4, stream);     // counts + cursor
  hipMemsetAsync(zerobuf, 0, 64 * 4, stream);

  hist_kernel<<<(E + 255) / 256, 256, 0, stream>>>(ei, counts, E);
  scan_kernel<<<1, SCAN_T, 0, stream>>>(counts, offsets, N);
  scatter_kernel<<<(E + 255) / 256, 256, 0, stream>>>(ei, offsets, cursor, csr, E);
  reduce_kernel<<<(N + 3) / 4, 256, 0, stream>>>(csr, offsets, counts, ea, mask, x,
                                                 outN, nrepb, N);
  wprep_kernel<<<(OUT_DIM * K2 + 255) / 256, 256, 0, stream>>>(W, Wtb);
  gemm_kernel<<<(E + BM - 1) / BM, 512, 0, stream>>>(ei, ea, nrepb, Wtb, b,
                                                     (const short*)zerobuf, outE, E);
}

// Round 3
// 473.970 us; speedup vs baseline: 3.1415x; 1.2592x over previous
//
#include <hip/hip_runtime.h>
#include <hip/hip_bf16.h>
#include <stdint.h>

typedef __attribute__((ext_vector_type(4))) float f32x4;
typedef __attribute__((ext_vector_type(8))) short bf16x8;

#define NDIM 6
#define IN_DIM 256
#define OUT_DIM 256
#define KW 780          // W inner dim (256*3 + 6*2)
#define NR 262          // node_rep row (256+6)
#define NRP 264         // padded node_rep row for 16B-aligned chunks
#define K2 832          // padded GEMM K = 13*64
#define BM 128
#define BK 64
#define NT 13
#define SCAN_T 1024

__device__ __forceinline__ short f2bf(float f) {
  return __builtin_bit_cast(short, __float2bfloat16(f));
}

__device__ __forceinline__ void gload_lds16(void* lds, const void* g) {
  __builtin_amdgcn_global_load_lds(
      (const __attribute__((address_space(1))) unsigned int*)g,
      (__attribute__((address_space(3))) unsigned int*)lds, 16, 0, 0);
}

// ---------------- CSR build: histogram of destination nodes ----------------
__global__ void hist_kernel(const int* __restrict__ ei, int* __restrict__ counts, int E) {
  int e = blockIdx.x * 256 + threadIdx.x;
  if (e < E) atomicAdd(&counts[ei[(long)E + e]], 1);
}

__global__ __launch_bounds__(SCAN_T) void scan_kernel(const int* __restrict__ counts,
                                                      int* __restrict__ offsets, int N) {
  __shared__ int part[SCAN_T];
  int t = threadIdx.x;
  int chunk = (N + SCAN_T - 1) / SCAN_T;
  int begin = t * chunk;
  int s = 0;
  for (int i = 0; i < chunk; ++i) {
    int idx = begin + i;
    if (idx < N) s += counts[idx];
  }
  part[t] = s;
  __syncthreads();
  for (int d = 1; d < SCAN_T; d <<= 1) {
    int v = (t >= d) ? part[t - d] : 0;
    __syncthreads();
    part[t] += v;
    __syncthreads();
  }
  int run = (t == 0) ? 0 : part[t - 1];
  for (int i = 0; i < chunk; ++i) {
    int idx = begin + i;
    if (idx < N) { offsets[idx] = run; run += counts[idx]; }
  }
}

__global__ void scatter_kernel(const int* __restrict__ ei, const int* __restrict__ offsets,
                               int* __restrict__ cursor, int* __restrict__ csr, int E) {
  int e = blockIdx.x * 256 + threadIdx.x;
  if (e >= E) return;
  int col = ei[(long)E + e];
  int pos = atomicAdd(&cursor[col], 1);
  csr[offsets[col] + pos] = e;
}

// ------- gather-reduce per node + node_rep emit (f32 out + bf16 copy) -------
__global__ __launch_bounds__(256) void reduce_kernel(
    const int* __restrict__ csr, const int* __restrict__ offsets,
    const int* __restrict__ counts, const float* __restrict__ ea,
    const float* __restrict__ mask, const float* __restrict__ x,
    float* __restrict__ outN, short* __restrict__ nrepb, int N) {
  int n = blockIdx.x * 4 + (threadIdx.x >> 6);
  if (n >= N) return;
  int lane = threadIdx.x & 63;
  int s = offsets[n], cnt = counts[n];
  f32x4 sum = (f32x4)0.0f;
  float den = 0.0f;
  for (int i = 0; i < cnt; ++i) {
    int e = csr[s + i];
    float m = mask[e];
    den += m;
    f32x4 v = ((const f32x4*)ea)[(long)e * 64 + lane];
    sum.x += v.x * m; sum.y += v.y * m; sum.z += v.z * m; sum.w += v.w * m;
  }
  float inv = 1.0f / (den + 1.0f);
  sum.x *= inv; sum.y *= inv; sum.z *= inv; sum.w *= inv;
  float* po = outN + (long)n * NR + lane * 4;
  po[0] = sum.x; po[1] = sum.y; po[2] = sum.z; po[3] = sum.w;
  short4 pb;
  pb.x = f2bf(sum.x); pb.y = f2bf(sum.y); pb.z = f2bf(sum.z); pb.w = f2bf(sum.w);
  *(short4*)(nrepb + (long)n * NRP + lane * 4) = pb;
  if (lane < NDIM) {
    float xv = x[(long)n * NDIM + lane];
    outN[(long)n * NR + IN_DIM + lane] = xv;
    nrepb[(long)n * NRP + IN_DIM + lane] = f2bf(xv);
  } else if (lane < 8) {
    nrepb[(long)n * NRP + IN_DIM + lane] = 0;
  }
}

// ---------------- W -> bf16, transposed to padded K layout [256][832] --------
// k' order: [ea(256) | nrep_row(264) | nrep_col(264) | pad(48)]
__global__ void wprep_kernel(const float* __restrict__ W, short* __restrict__ Wtb) {
  int idx = blockIdx.x * 256 + threadIdx.x;
  if (idx >= OUT_DIM * K2) return;
  int n = idx / K2, k = idx % K2;
  float v = 0.0f;
  if (k < 256) {
    v = W[(long)n * KW + 524 + k];
  } else if (k < 520) {
    int kk = k - 256; if (kk < NR) v = W[(long)n * KW + kk];
  } else if (k < 784) {
    int kk = k - 520; if (kk < NR) v = W[(long)n * KW + NR + kk];
  }
  Wtb[idx] = f2bf(v);
}

// ---------------- fused gather + GEMM: out = [nr[row],nr[col],ea] @ W^T + b --
// T3/T4 structure: 3-deep LDS pipeline, compute reads LDS only, counted vmcnt.
__global__ __launch_bounds__(512, 2) void gemm_kernel(
    const int* __restrict__ ei, const float* __restrict__ ea,
    const short* __restrict__ nrepb, const short* __restrict__ Wtb,
    const float* __restrict__ bias, const short* __restrict__ zerobuf,
    float* __restrict__ outE, int E) {
  __shared__ short As[3][BM * BK];        // 16 KB x3
  __shared__ short Bs[3][OUT_DIM * BK];   // 32 KB x3

  const int tid = threadIdx.x;
  const int wave = tid >> 6, lane = tid & 63;
  const long e0 = (long)blockIdx.x * BM;
  const int wm = wave >> 2, wn = wave & 3;      // 2M x 4N wave grid
  const int mbase = wm * 64, nbase = wn * 64;

  // bias first so in-loop vmem = staging only (keeps vmcnt ledger exact)
  float bvals[4];
#pragma unroll
  for (int nf = 0; nf < 4; ++nf) bvals[nf] = bias[nbase + 16 * nf + (lane & 15)];

  // staging geometry
  const int scp = lane & 7;
  int srow[2], ridx[2], cidx[2];
  srow[0] = 16 * wave + (lane >> 3);
  srow[1] = srow[0] + 8;
#pragma unroll
  for (int i = 0; i < 2; ++i) {
    long ec = e0 + srow[i]; if (ec >= E) ec = E - 1;
    ridx[i] = ei[ec];
    cidx[i] = ei[(long)E + ec];
  }
  // ea reg-staging geometry: thread covers rows g>>3 (g = tid, tid+512), chunk-pos tid&7
  const int earow[2] = { tid >> 3, (tid + 512) >> 3 };
  const int eacp = tid & 7;

  f32x4 acc[4][4];
#pragma unroll
  for (int mf = 0; mf < 4; ++mf)
#pragma unroll
    for (int nf = 0; nf < 4; ++nf) acc[mf][nf] = (f32x4)0.0f;

  f32x4 eahold[2][4];  // [tile&1][i*2+j] — statically indexed via full unroll

  // T14 issue-early: global f32 loads for ea tile (tiles 0..3)
  auto ea_issue = [&](int t) {
#pragma unroll
    for (int i = 0; i < 2; ++i) {
      int row = earow[i];
      int c = eacp ^ (row & 7);
      int k = t * BK + 8 * c;
      long e = e0 + row; if (e >= E) e = E - 1;
      const f32x4* s = (const f32x4*)(ea + (e * IN_DIM + k));
      eahold[t & 1][i * 2] = s[0];
      eahold[t & 1][i * 2 + 1] = s[1];
    }
  };
  // T14 write-late: convert + swizzled ds_write
  auto ea_write = [&](int t) {
#pragma unroll
    for (int i = 0; i < 2; ++i) {
      int row = earow[i];
      f32x4 v0 = eahold[t & 1][i * 2], v1 = eahold[t & 1][i * 2 + 1];
      bf16x8 p;
      p[0] = f2bf(v0.x); p[1] = f2bf(v0.y); p[2] = f2bf(v0.z); p[3] = f2bf(v0.w);
      p[4] = f2bf(v1.x); p[5] = f2bf(v1.y); p[6] = f2bf(v1.z); p[7] = f2bf(v1.w);
      *(bf16x8*)&As[t % 3][row * BK + eacp * 8] = p;
    }
  };

  auto stage_nr = [&](int t) {  // tiles 4..12: A via global_load_lds, pre-swizzled src
#pragma unroll
    for (int i = 0; i < 2; ++i) {
      int row = srow[i];
      int c = scp ^ (row & 7);
      int k = t * BK + 8 * c;
      const short* src;
      if (k < 520)      src = nrepb + (long)ridx[i] * NRP + (k - 256);
      else if (k < 784) src = nrepb + (long)cidx[i] * NRP + (k - 520);
      else              src = zerobuf;
      gload_lds16(&As[t % 3][(16 * wave + i * 8) * BK], src);
    }
  };

  auto stage_B = [&](int t) {  // B tile via global_load_lds, pre-swizzled src
#pragma unroll
    for (int i = 0; i < 4; ++i) {
      int nrow = 32 * wave + 8 * i + (lane >> 3);
      int c = scp ^ (nrow & 7);
      const short* src = Wtb + (long)nrow * K2 + t * BK + 8 * c;
      gload_lds16(&Bs[t % 3][(32 * wave + 8 * i) * BK], src);
    }
  };

  auto compute = [&](int t) {
#pragma unroll
    for (int s2 = 0; s2 < 2; ++s2) {
      bf16x8 a[4], bv[4];
      int cl = s2 * 4 + (lane >> 4);
#pragma unroll
      for (int mf = 0; mf < 4; ++mf) {
        int m = mbase + 16 * mf + (lane & 15);
        a[mf] = *(const bf16x8*)&As[t % 3][m * BK + ((cl ^ (m & 7)) * 8)];
      }
#pragma unroll
      for (int nf = 0; nf < 4; ++nf) {
        int n = nbase + 16 * nf + (lane & 15);
        bv[nf] = *(const bf16x8*)&Bs[t % 3][n * BK + ((cl ^ (n & 7)) * 8)];
      }
      __builtin_amdgcn_s_setprio(1);
#pragma unroll
      for (int mf = 0; mf < 4; ++mf)
#pragma unroll
        for (int nf = 0; nf < 4; ++nf)
          acc[mf][nf] = __builtin_amdgcn_mfma_f32_16x16x32_bf16(a[mf], bv[nf], acc[mf][nf], 0, 0, 0);
      __builtin_amdgcn_s_setprio(0);
    }
  };

  // ---- prologue: stage tiles 0,1 ----
  ea_issue(0); ea_issue(1);
  stage_B(0); stage_B(1);
  ea_write(0);
  asm volatile("s_waitcnt vmcnt(8) lgkmcnt(0)" ::: "memory");
  __builtin_amdgcn_s_barrier();
  __builtin_amdgcn_sched_barrier(0);

  // ---- main loop: one barrier per tile, counted vmcnt (never 0 until drain) ----
#pragma unroll
  for (int t = 0; t < NT; ++t) {
    if (t + 2 < 4) ea_issue(t + 2);                    // t = 0,1
    if (t + 1 < 4) ea_write(t + 1);                    // t = 0,1,2
    if (t + 2 >= 4 && t + 2 < NT) stage_nr(t + 2);     // t = 2..10
    if (t + 2 < NT) stage_B(t + 2);                    // t = 0..10
    compute(t);
    if (t < NT - 1) {
      if (t < 2)        asm volatile("s_waitcnt vmcnt(8) lgkmcnt(0)" ::: "memory");
      else if (t < 11)  asm volatile("s_waitcnt vmcnt(6) lgkmcnt(0)" ::: "memory");
      else              asm volatile("s_waitcnt vmcnt(0) lgkmcnt(0)" ::: "memory");
      __builtin_amdgcn_s_barrier();
      __builtin_amdgcn_sched_barrier(0);
    }
  }

  // ---- epilogue: C layout col=lane&15, row=(lane>>4)*4+reg ----
#pragma unroll
  for (int mf = 0; mf < 4; ++mf) {
#pragma unroll
    for (int nf = 0; nf < 4; ++nf) {
#pragma unroll
      for (int q = 0; q < 4; ++q) {
        long e = e0 + mbase + 16 * mf + (lane >> 4) * 4 + q;
        if (e < E)
          outE[e * OUT_DIM + nbase + 16 * nf + (lane & 15)] = acc[mf][nf][q] + bvals[nf];
      }
    }
  }
}

extern "C" void kernel_launch(void* const* d_in, const int* in_sizes, int n_in,
                              void* d_out, int out_size, void* d_ws, size_t ws_size,
                              hipStream_t stream) {
  const float* x    = (const float*)d_in[0];
  const int*   ei   = (const int*)d_in[2];
  const float* ea   = (const float*)d_in[3];
  const float* mask = (const float*)d_in[4];
  const float* W    = (const float*)d_in[5];
  const float* b    = (const float*)d_in[6];
  const int E = in_sizes[4];
  const int N = in_sizes[0] / NDIM;

  // ws layout
  char* p = (char*)d_ws;
  int* counts  = (int*)p; p += (long)N * 4;
  int* cursor  = (int*)p; p += (long)N * 4;
  int* offsets = (int*)p; p += (long)(N + 1) * 4;
  int* csr     = (int*)p; p += (long)E * 4;
  p = (char*)(((uintptr_t)p + 15) & ~(uintptr_t)15);
  float* zerobuf = (float*)p; p += 64 * 4;
  short* nrepb   = (short*)p; p += (long)N * NRP * 2;
  short* Wtb     = (short*)p;

  float* outN = (float*)d_out;
  float* outE = outN + (long)N * NR;

  hipMemsetAsync(counts, 0, (size_t)2 * N * 4, stream);     // counts + cursor
  hipMemsetAsync(zerobuf, 0, 64 * 4, stream);

  hist_kernel<<<(E + 255) / 256, 256, 0, stream>>>(ei, counts, E);
  scan_kernel<<<1, SCAN_T, 0, stream>>>(counts, offsets, N);
  scatter_kernel<<<(E + 255) / 256, 256, 0, stream>>>(ei, offsets, cursor, csr, E);
  reduce_kernel<<<(N + 3) / 4, 256, 0, stream>>>(csr, offsets, counts, ea, mask, x,
                                                 outN, nrepb, N);
  wprep_kernel<<<(OUT_DIM * K2 + 255) / 256, 256, 0, stream>>>(W, Wtb);
  gemm_kernel<<<(E + BM - 1) / BM, 512, 0, stream>>>(ei, ea, nrepb, Wtb, b,
                                                     (const short*)zerobuf, outE, E);
}

// Round 4
// 462.510 us; speedup vs baseline: 3.2193x; 1.0248x over previous
//
#include <hip/hip_runtime.h>
#include <hip/hip_bf16.h>
#include <stdint.h>

typedef __attribute__((ext_vector_type(4))) float f32x4;
typedef __attribute__((ext_vector_type(8))) short bf16x8;

#define NDIM 6
#define IN_DIM 256
#define OUT_DIM 256
#define KW 780          // W inner dim (256*3 + 6*2)
#define NR 262          // node_rep row (256+6)
#define NRP 264         // padded node_rep row for 16B-aligned chunks
#define K2 832          // padded GEMM K = 13*64
#define BM 64
#define BK 64
#define NT 13
#define SCAN_T 1024

__device__ __forceinline__ short f2bf(float f) {
  return __builtin_bit_cast(short, __float2bfloat16(f));
}

__device__ __forceinline__ void gload_lds16(void* lds, const void* g) {
  __builtin_amdgcn_global_load_lds(
      (const __attribute__((address_space(1))) unsigned int*)g,
      (__attribute__((address_space(3))) unsigned int*)lds, 16, 0, 0);
}

// ---------------- CSR build: histogram of destination nodes ----------------
__global__ void hist_kernel(const int* __restrict__ ei, int* __restrict__ counts, int E) {
  int e = blockIdx.x * 256 + threadIdx.x;
  if (e < E) atomicAdd(&counts[ei[(long)E + e]], 1);
}

__global__ __launch_bounds__(SCAN_T) void scan_kernel(const int* __restrict__ counts,
                                                      int* __restrict__ offsets, int N) {
  __shared__ int part[SCAN_T];
  int t = threadIdx.x;
  int chunk = (N + SCAN_T - 1) / SCAN_T;
  int begin = t * chunk;
  int s = 0;
  for (int i = 0; i < chunk; ++i) {
    int idx = begin + i;
    if (idx < N) s += counts[idx];
  }
  part[t] = s;
  __syncthreads();
  for (int d = 1; d < SCAN_T; d <<= 1) {
    int v = (t >= d) ? part[t - d] : 0;
    __syncthreads();
    part[t] += v;
    __syncthreads();
  }
  int run = (t == 0) ? 0 : part[t - 1];
  for (int i = 0; i < chunk; ++i) {
    int idx = begin + i;
    if (idx < N) { offsets[idx] = run; run += counts[idx]; }
  }
}

__global__ void scatter_kernel(const int* __restrict__ ei, const int* __restrict__ offsets,
                               int* __restrict__ cursor, int* __restrict__ csr, int E) {
  int e = blockIdx.x * 256 + threadIdx.x;
  if (e >= E) return;
  int col = ei[(long)E + e];
  int pos = atomicAdd(&cursor[col], 1);
  csr[offsets[col] + pos] = e;
}

// ------- gather-reduce per node + node_rep emit (f32 out + bf16 copy) -------
__global__ __launch_bounds__(256) void reduce_kernel(
    const int* __restrict__ csr, const int* __restrict__ offsets,
    const int* __restrict__ counts, const float* __restrict__ ea,
    const float* __restrict__ mask, const float* __restrict__ x,
    float* __restrict__ outN, short* __restrict__ nrepb, int N) {
  int n = blockIdx.x * 4 + (threadIdx.x >> 6);
  if (n >= N) return;
  int lane = threadIdx.x & 63;
  int s = offsets[n], cnt = counts[n];
  f32x4 sum = (f32x4)0.0f;
  float den = 0.0f;
#pragma unroll 4
  for (int i = 0; i < cnt; ++i) {
    int e = csr[s + i];
    float m = mask[e];
    den += m;
    f32x4 v = ((const f32x4*)ea)[(long)e * 64 + lane];
    sum.x += v.x * m; sum.y += v.y * m; sum.z += v.z * m; sum.w += v.w * m;
  }
  float inv = 1.0f / (den + 1.0f);
  sum.x *= inv; sum.y *= inv; sum.z *= inv; sum.w *= inv;
  float* po = outN + (long)n * NR + lane * 4;
  po[0] = sum.x; po[1] = sum.y; po[2] = sum.z; po[3] = sum.w;
  short4 pb;
  pb.x = f2bf(sum.x); pb.y = f2bf(sum.y); pb.z = f2bf(sum.z); pb.w = f2bf(sum.w);
  *(short4*)(nrepb + (long)n * NRP + lane * 4) = pb;
  if (lane < NDIM) {
    float xv = x[(long)n * NDIM + lane];
    outN[(long)n * NR + IN_DIM + lane] = xv;
    nrepb[(long)n * NRP + IN_DIM + lane] = f2bf(xv);
  } else if (lane < 8) {
    nrepb[(long)n * NRP + IN_DIM + lane] = 0;
  }
}

// ---------------- W -> bf16, transposed to padded K layout [256][832] --------
// k' order: [ea(256) | nrep_row(264) | nrep_col(264) | pad(48)]
__global__ void wprep_kernel(const float* __restrict__ W, short* __restrict__ Wtb) {
  int idx = blockIdx.x * 256 + threadIdx.x;
  if (idx >= OUT_DIM * K2) return;
  int n = idx / K2, k = idx % K2;
  float v = 0.0f;
  if (k < 256) {
    v = W[(long)n * KW + 524 + k];
  } else if (k < 520) {
    int kk = k - 256; if (kk < NR) v = W[(long)n * KW + kk];
  } else if (k < 784) {
    int kk = k - 520; if (kk < NR) v = W[(long)n * KW + NR + kk];
  }
  Wtb[idx] = f2bf(v);
}

// ---------------- fused gather + GEMM: out = [nr[row],nr[col],ea] @ W^T + b --
// BM=64, 4 waves (each owns a 64-col n-quadrant). A-only LDS (8 slots):
// slots 0-3 = ea tiles (prologue), 4-7 = rotating nr tiles. B direct from L2
// into reg double-buffer, 1 tile ahead. Counted vmcnt; 2 blocks/CU.
__global__ __launch_bounds__(256, 2) void gemm_kernel(
    const int* __restrict__ ei, const float* __restrict__ ea,
    const short* __restrict__ nrepb, const short* __restrict__ Wtb,
    const float* __restrict__ bias, const short* __restrict__ zerobuf,
    float* __restrict__ outE, int E) {
  __shared__ short As[8][BM * BK];   // 8 x 8 KB = 64 KB

  const int tid = threadIdx.x;
  const int wave = tid >> 6, lane = tid & 63;
  const long e0 = (long)blockIdx.x * BM;
  const int nbase = wave * 64;

  // bias first (drained by prologue's compiler waits; epilogue-only use)
  float bvals[4];
#pragma unroll
  for (int nf = 0; nf < 4; ++nf) bvals[nf] = bias[nbase + 16 * nf + (lane & 15)];

  // nr staging geometry: wave covers rows [16w,16w+16), lane -> row 16w+8i+(lane>>3), chunk lane&7
  const int scp = lane & 7;
  int srow[2], ridx[2], cidx[2];
  srow[0] = 16 * wave + (lane >> 3);
  srow[1] = srow[0] + 8;
#pragma unroll
  for (int i = 0; i < 2; ++i) {
    long ec = e0 + srow[i]; if (ec >= E) ec = E - 1;
    ridx[i] = ei[ec];
    cidx[i] = ei[(long)E + ec];
  }

  f32x4 acc[4][4];
#pragma unroll
  for (int mf = 0; mf < 4; ++mf)
#pragma unroll
    for (int nf = 0; nf < 4; ++nf) acc[mf][nf] = (f32x4)0.0f;

  bf16x8 bv[2][8];  // B reg double-buffer; all indices static under full unroll

  auto loadB = [&](int tt, int tb) {
#pragma unroll
    for (int s2 = 0; s2 < 2; ++s2)
#pragma unroll
      for (int nf = 0; nf < 4; ++nf)
        bv[tb][s2 * 4 + nf] = *(const bf16x8*)&Wtb[
            (long)(nbase + nf * 16 + (lane & 15)) * K2 + tt * BK + s2 * 32 + (lane >> 4) * 8];
  };

  auto stage_nr = [&](int t) {  // tiles 4..12 -> slot (t&3)+4, pre-swizzled per-lane src
#pragma unroll
    for (int i = 0; i < 2; ++i) {
      int row = srow[i];
      int c = scp ^ (row & 7);
      int k = t * BK + 8 * c;
      const short* src;
      if (k < 520)      src = nrepb + (long)ridx[i] * NRP + (k - 256);
      else if (k < 784) src = nrepb + (long)cidx[i] * NRP + (k - 520);
      else              src = zerobuf;
      gload_lds16(&As[(t & 3) + 4][(16 * wave + i * 8) * BK], src);
    }
  };

  auto compute = [&](int t, int slot) {
#pragma unroll
    for (int s2 = 0; s2 < 2; ++s2) {
      bf16x8 a[4];
      int cl = s2 * 4 + (lane >> 4);
#pragma unroll
      for (int mf = 0; mf < 4; ++mf) {
        int m = 16 * mf + (lane & 15);
        a[mf] = *(const bf16x8*)&As[slot][m * BK + ((cl ^ (m & 7)) * 8)];
      }
      __builtin_amdgcn_s_setprio(1);
#pragma unroll
      for (int mf = 0; mf < 4; ++mf)
#pragma unroll
        for (int nf = 0; nf < 4; ++nf)
          acc[mf][nf] = __builtin_amdgcn_mfma_f32_16x16x32_bf16(
              a[mf], bv[t & 1][s2 * 4 + nf], acc[mf][nf], 0, 0, 0);
      __builtin_amdgcn_s_setprio(0);
    }
  };

  // ---- prologue: issue ALL ea loads + B(0) + A(4),A(5); then convert+write ----
  f32x4 eh[4][2][2];
#pragma unroll
  for (int t = 0; t < 4; ++t)
#pragma unroll
    for (int i = 0; i < 2; ++i) {
      int g = tid + i * 256;
      int row = g >> 3, cp = g & 7;
      int c = cp ^ (row & 7);
      long e = e0 + row; if (e >= E) e = E - 1;
      const f32x4* s = (const f32x4*)(ea + (e * IN_DIM + t * BK + 8 * c));
      eh[t][i][0] = s[0];
      eh[t][i][1] = s[1];
    }
  loadB(0, 0);
  stage_nr(4);
  stage_nr(5);
  __builtin_amdgcn_sched_barrier(0);   // pin: all issues above, converts below
#pragma unroll
  for (int t = 0; t < 4; ++t)
#pragma unroll
    for (int i = 0; i < 2; ++i) {
      int g = tid + i * 256;
      int row = g >> 3, cp = g & 7;
      f32x4 v0 = eh[t][i][0], v1 = eh[t][i][1];
      bf16x8 p;
      p[0] = f2bf(v0.x); p[1] = f2bf(v0.y); p[2] = f2bf(v0.z); p[3] = f2bf(v0.w);
      p[4] = f2bf(v1.x); p[5] = f2bf(v1.y); p[6] = f2bf(v1.z); p[7] = f2bf(v1.w);
      *(bf16x8*)&As[t][row * BK + cp * 8] = p;
    }
  // outstanding vmem: [B0 8][A4 2][A5 2] -> vmcnt(4) guarantees B0 landed
  asm volatile("s_waitcnt vmcnt(4) lgkmcnt(0)" ::: "memory");
  __builtin_amdgcn_s_barrier();
  __builtin_amdgcn_sched_barrier(0);

  // ---- main loop, fully unrolled; ledger verified per-iter ----
  // t=0: out 12 (A4,A5,B1) none needed | t=1..3: vmcnt(8) | t=4..10: vmcnt(10)
  // t=11: vmcnt(8) | t=12: vmcnt(0); barrier every iter except t=12
#pragma unroll
  for (int t = 0; t < NT; ++t) {
    if (t >= 4 && t <= 10) stage_nr(t + 2);
    if (t + 1 < NT) loadB(t + 1, (t + 1) & 1);
    if (t >= 1 && t <= 3)        asm volatile("s_waitcnt vmcnt(8)" ::: "memory");
    else if (t >= 4 && t <= 10)  asm volatile("s_waitcnt vmcnt(10)" ::: "memory");
    else if (t == 11)            asm volatile("s_waitcnt vmcnt(8)" ::: "memory");
    else if (t == 12)            asm volatile("s_waitcnt vmcnt(0)" ::: "memory");
    if (t < 12) {
      __builtin_amdgcn_s_barrier();
      __builtin_amdgcn_sched_barrier(0);
    }
    compute(t, t < 4 ? t : (t & 3) + 4);
  }

  // ---- epilogue: C layout col=lane&15, row=(lane>>4)*4+reg ----
#pragma unroll
  for (int mf = 0; mf < 4; ++mf) {
#pragma unroll
    for (int nf = 0; nf < 4; ++nf) {
#pragma unroll
      for (int q = 0; q < 4; ++q) {
        long e = e0 + 16 * mf + (lane >> 4) * 4 + q;
        if (e < E)
          outE[e * OUT_DIM + nbase + 16 * nf + (lane & 15)] = acc[mf][nf][q] + bvals[nf];
      }
    }
  }
}

extern "C" void kernel_launch(void* const* d_in, const int* in_sizes, int n_in,
                              void* d_out, int out_size, void* d_ws, size_t ws_size,
                              hipStream_t stream) {
  const float* x    = (const float*)d_in[0];
  const int*   ei   = (const int*)d_in[2];
  const float* ea   = (const float*)d_in[3];
  const float* mask = (const float*)d_in[4];
  const float* W    = (const float*)d_in[5];
  const float* b    = (const float*)d_in[6];
  const int E = in_sizes[4];
  const int N = in_sizes[0] / NDIM;

  // ws layout
  char* p = (char*)d_ws;
  int* counts  = (int*)p; p += (long)N * 4;
  int* cursor  = (int*)p; p += (long)N * 4;
  int* offsets = (int*)p; p += (long)(N + 1) * 4;
  int* csr     = (int*)p; p += (long)E * 4;
  p = (char*)(((uintptr_t)p + 15) & ~(uintptr_t)15);
  float* zerobuf = (float*)p; p += 64 * 4;
  short* nrepb   = (short*)p; p += (long)N * NRP * 2;
  short* Wtb     = (short*)p;

  float* outN = (float*)d_out;
  float* outE = outN + (long)N * NR;

  hipMemsetAsync(counts, 0, (size_t)2 * N * 4, stream);     // counts + cursor
  hipMemsetAsync(zerobuf, 0, 64 * 4, stream);

  hist_kernel<<<(E + 255) / 256, 256, 0, stream>>>(ei, counts, E);
  scan_kernel<<<1, SCAN_T, 0, stream>>>(counts, offsets, N);
  scatter_kernel<<<(E + 255) / 256, 256, 0, stream>>>(ei, offsets, cursor, csr, E);
  reduce_kernel<<<(N + 3) / 4, 256, 0, stream>>>(csr, offsets, counts, ea, mask, x,
                                                 outN, nrepb, N);
  wprep_kernel<<<(OUT_DIM * K2 + 255) / 256, 256, 0, stream>>>(W, Wtb);
  gemm_kernel<<<(E + BM - 1) / BM, 256, 0, stream>>>(ei, ea, nrepb, Wtb, b,
                                                     (const short*)zerobuf, outE, E);
}

// Round 5
// 391.998 us; speedup vs baseline: 3.7984x; 1.1799x over previous
//
#include <hip/hip_runtime.h>
#include <hip/hip_bf16.h>
#include <stdint.h>

typedef __attribute__((ext_vector_type(4))) float f32x4;
typedef __attribute__((ext_vector_type(8))) short bf16x8;

#define NDIM 6
#define IN_DIM 256
#define OUT_DIM 256
#define KW 780          // W inner dim (256*3 + 6*2)
#define NR 262          // node_rep row (256+6)
#define NRP 320         // padded node_rep row: 5 x 64-k tiles for P-GEMM
#define SCAN_T 1024

__device__ __forceinline__ short f2bf(float f) {
  return __builtin_bit_cast(short, __float2bfloat16(f));
}

__device__ __forceinline__ void gload_lds16(void* lds, const void* g) {
  __builtin_amdgcn_global_load_lds(
      (const __attribute__((address_space(1))) unsigned int*)g,
      (__attribute__((address_space(3))) unsigned int*)lds, 16, 0, 0);
}

// ---------------- CSR build ----------------
__global__ void hist_kernel(const int* __restrict__ ei, int* __restrict__ counts, int E) {
  int e = blockIdx.x * 256 + threadIdx.x;
  if (e < E) atomicAdd(&counts[ei[(long)E + e]], 1);
}

__global__ __launch_bounds__(SCAN_T) void scan_kernel(const int* __restrict__ counts,
                                                      int* __restrict__ offsets, int N) {
  __shared__ int part[SCAN_T];
  int t = threadIdx.x;
  int chunk = (N + SCAN_T - 1) / SCAN_T;
  int begin = t * chunk;
  int s = 0;
  for (int i = 0; i < chunk; ++i) {
    int idx = begin + i;
    if (idx < N) s += counts[idx];
  }
  part[t] = s;
  __syncthreads();
  for (int d = 1; d < SCAN_T; d <<= 1) {
    int v = (t >= d) ? part[t - d] : 0;
    __syncthreads();
    part[t] += v;
    __syncthreads();
  }
  int run = (t == 0) ? 0 : part[t - 1];
  for (int i = 0; i < chunk; ++i) {
    int idx = begin + i;
    if (idx < N) { offsets[idx] = run; run += counts[idx]; }
  }
}

__global__ void scatter_kernel(const int* __restrict__ ei, const int* __restrict__ offsets,
                               int* __restrict__ cursor, int* __restrict__ csr, int E) {
  int e = blockIdx.x * 256 + threadIdx.x;
  if (e >= E) return;
  int col = ei[(long)E + e];
  int pos = atomicAdd(&cursor[col], 1);
  csr[offsets[col] + pos] = e;
}

// ------- gather-reduce per node + node_rep emit (f32 out + bf16 copy) -------
__global__ __launch_bounds__(256) void reduce_kernel(
    const int* __restrict__ csr, const int* __restrict__ offsets,
    const int* __restrict__ counts, const float* __restrict__ ea,
    const float* __restrict__ mask, const float* __restrict__ x,
    float* __restrict__ outN, short* __restrict__ nrepb, int N) {
  int n = blockIdx.x * 4 + (threadIdx.x >> 6);
  if (n >= N) return;
  int lane = threadIdx.x & 63;
  int s = offsets[n], cnt = counts[n];
  f32x4 sum = (f32x4)0.0f;
  float den = 0.0f;
#pragma unroll 4
  for (int i = 0; i < cnt; ++i) {
    int e = csr[s + i];
    float m = mask[e];
    den += m;
    f32x4 v = ((const f32x4*)ea)[(long)e * 64 + lane];
    sum.x += v.x * m; sum.y += v.y * m; sum.z += v.z * m; sum.w += v.w * m;
  }
  float inv = 1.0f / (den + 1.0f);
  sum.x *= inv; sum.y *= inv; sum.z *= inv; sum.w *= inv;
  float* po = outN + (long)n * NR + lane * 4;
  po[0] = sum.x; po[1] = sum.y; po[2] = sum.z; po[3] = sum.w;
  short4 pb;
  pb.x = f2bf(sum.x); pb.y = f2bf(sum.y); pb.z = f2bf(sum.z); pb.w = f2bf(sum.w);
  *(short4*)(nrepb + (long)n * NRP + lane * 4) = pb;
  if (lane < NDIM) {
    float xv = x[(long)n * NDIM + lane];
    outN[(long)n * NR + IN_DIM + lane] = xv;
    nrepb[(long)n * NRP + IN_DIM + lane] = f2bf(xv);
  } else if (lane < 8) {
    nrepb[(long)n * NRP + IN_DIM + lane] = 0;  // cols 262,263 -> 0
  }
  // cols 264..319 remain untouched; W pad columns are 0 so their product is 0
}

// -------- W -> bf16 splits: Weat [256][256], Wrt/Wct [256][320] (pad 0) -----
__global__ void wprep_kernel(const float* __restrict__ W, short* __restrict__ Weat,
                             short* __restrict__ Wrt, short* __restrict__ Wct) {
  int idx = blockIdx.x * 256 + threadIdx.x;
  if (idx < OUT_DIM * 256) {
    int n = idx >> 8, k = idx & 255;
    Weat[idx] = f2bf(W[(long)n * KW + 2 * NR + k]);
    return;
  }
  idx -= OUT_DIM * 256;
  if (idx < OUT_DIM * NRP) {
    int n = idx / NRP, k = idx % NRP;
    Wrt[idx] = f2bf(k < NR ? W[(long)n * KW + k] : 0.0f);
    return;
  }
  idx -= OUT_DIM * NRP;
  if (idx < OUT_DIM * NRP) {
    int n = idx / NRP, k = idx % NRP;
    Wct[idx] = f2bf(k < NR ? W[(long)n * KW + NR + k] : 0.0f);
  }
}

// ---------------- P-GEMM: P_r = nrep@Wr^T + b ; P_c = nrep@Wc^T -------------
// grid (ceil(N/64), 2); 256 threads; wave owns 64-col n-quadrant; K=320 (5 tiles)
__global__ __launch_bounds__(256, 2) void pgemm_kernel(
    const short* __restrict__ nrepb, const short* __restrict__ Wrt,
    const short* __restrict__ Wct, const float* __restrict__ bias,
    float* __restrict__ Pr, float* __restrict__ Pc, int N) {
  __shared__ short As[5][64 * 64];   // 40 KB
  const int tid = threadIdx.x;
  const int wave = tid >> 6, lane = tid & 63;
  const int m0 = blockIdx.x * 64;
  const int table = blockIdx.y;
  const short* Wt = table ? Wct : Wrt;
  float* P = table ? Pc : Pr;
  const int nbase = wave * 64;

  float bvals[4];
#pragma unroll
  for (int nf = 0; nf < 4; ++nf)
    bvals[nf] = table ? 0.0f : bias[nbase + 16 * nf + (lane & 15)];

  f32x4 acc[4][4];
#pragma unroll
  for (int mf = 0; mf < 4; ++mf)
#pragma unroll
    for (int nf = 0; nf < 4; ++nf) acc[mf][nf] = (f32x4)0.0f;

  bf16x8 bv[2][8];
  auto loadB = [&](int t, int tb) {
#pragma unroll
    for (int s2 = 0; s2 < 2; ++s2)
#pragma unroll
      for (int nf = 0; nf < 4; ++nf)
        bv[tb][s2 * 4 + nf] = *(const bf16x8*)&Wt[
            (long)(nbase + nf * 16 + (lane & 15)) * NRP + t * 64 + s2 * 32 + (lane >> 4) * 8];
  };

  // stage ALL 5 A-tiles via global_load_lds (pre-swizzled source, linear dest)
  const int scp = lane & 7;
#pragma unroll
  for (int t = 0; t < 5; ++t)
#pragma unroll
    for (int i = 0; i < 2; ++i) {
      int row = 16 * wave + 8 * i + (lane >> 3);
      int c = scp ^ (row & 7);
      long m = m0 + row; if (m >= N) m = N - 1;
      gload_lds16(&As[t][(16 * wave + 8 * i) * 64], nrepb + m * NRP + t * 64 + 8 * c);
    }
  loadB(0, 0);
  asm volatile("s_waitcnt vmcnt(8)" ::: "memory");   // A landed; B0 in flight
  __builtin_amdgcn_s_barrier();
  __builtin_amdgcn_sched_barrier(0);

#pragma unroll
  for (int t = 0; t < 5; ++t) {
    if (t < 4) loadB(t + 1, (t + 1) & 1);
    if (t < 4) asm volatile("s_waitcnt vmcnt(8)" ::: "memory");
    else       asm volatile("s_waitcnt vmcnt(0)" ::: "memory");
#pragma unroll
    for (int s2 = 0; s2 < 2; ++s2) {
      bf16x8 a[4];
      int cl = s2 * 4 + (lane >> 4);
#pragma unroll
      for (int mf = 0; mf < 4; ++mf) {
        int m = 16 * mf + (lane & 15);
        a[mf] = *(const bf16x8*)&As[t][m * 64 + ((cl ^ (m & 7)) * 8)];
      }
#pragma unroll
      for (int mf = 0; mf < 4; ++mf)
#pragma unroll
        for (int nf = 0; nf < 4; ++nf)
          acc[mf][nf] = __builtin_amdgcn_mfma_f32_16x16x32_bf16(
              a[mf], bv[t & 1][s2 * 4 + nf], acc[mf][nf], 0, 0, 0);
    }
  }

#pragma unroll
  for (int mf = 0; mf < 4; ++mf)
#pragma unroll
    for (int nf = 0; nf < 4; ++nf)
#pragma unroll
      for (int q = 0; q < 4; ++q) {
        long m = m0 + 16 * mf + (lane >> 4) * 4 + q;
        if (m < N)
          P[m * OUT_DIM + nbase + 16 * nf + (lane & 15)] = acc[mf][nf][q] + bvals[nf];
      }
}

// ------ edge GEMM: out[e] = ea[e]@Weat^T + Pr[row[e]] + Pc[col[e]] ----------
// BM=64, K=256 (4 tiles). A staged once (f32->bf16), ONE barrier, no in-loop
// barriers; B per-wave reg dbuf from L2; P-add fused in epilogue.
__global__ __launch_bounds__(256, 2) void egemm_kernel(
    const int* __restrict__ ei, const float* __restrict__ ea,
    const short* __restrict__ Weat, const float* __restrict__ Pr,
    const float* __restrict__ Pc, float* __restrict__ outE, int E) {
  __shared__ short As[4][64 * 64];   // 32 KB
  const int tid = threadIdx.x;
  const int wave = tid >> 6, lane = tid & 63;
  const long e0 = (long)blockIdx.x * 64;
  const int nbase = wave * 64;

  f32x4 acc[4][4];
#pragma unroll
  for (int mf = 0; mf < 4; ++mf)
#pragma unroll
    for (int nf = 0; nf < 4; ++nf) acc[mf][nf] = (f32x4)0.0f;

  bf16x8 bv[2][8];
  auto loadB = [&](int t, int tb) {
#pragma unroll
    for (int s2 = 0; s2 < 2; ++s2)
#pragma unroll
      for (int nf = 0; nf < 4; ++nf)
        bv[tb][s2 * 4 + nf] = *(const bf16x8*)&Weat[
            (nbase + nf * 16 + (lane & 15)) * 256 + t * 64 + s2 * 32 + (lane >> 4) * 8];
  };

  // ---- stage all 4 A-tiles: 64 rows x 256 k, f32 -> bf16, swizzled writes ----
  f32x4 eh[8][2];
#pragma unroll
  for (int j = 0; j < 8; ++j) {
    int c8 = tid + j * 256;                 // bf16x8-chunk index in 64x256 tile
    int row = c8 >> 5, cp8 = c8 & 31;
    long e = e0 + row; if (e >= E) e = E - 1;
    const f32x4* s = (const f32x4*)(ea + (e * IN_DIM + cp8 * 8));
    eh[j][0] = s[0];
    eh[j][1] = s[1];
  }
  loadB(0, 0);
  __builtin_amdgcn_sched_barrier(0);        // pin: all issues above, converts below
#pragma unroll
  for (int j = 0; j < 8; ++j) {
    int c8 = tid + j * 256;
    int row = c8 >> 5, cp8 = c8 & 31;
    int t = cp8 >> 3, cp = cp8 & 7;
    f32x4 v0 = eh[j][0], v1 = eh[j][1];
    bf16x8 p;
    p[0] = f2bf(v0.x); p[1] = f2bf(v0.y); p[2] = f2bf(v0.z); p[3] = f2bf(v0.w);
    p[4] = f2bf(v1.x); p[5] = f2bf(v1.y); p[6] = f2bf(v1.z); p[7] = f2bf(v1.w);
    *(bf16x8*)&As[t][row * 64 + ((cp ^ (row & 7)) * 8)] = p;
  }
  asm volatile("s_waitcnt lgkmcnt(0)" ::: "memory");
  __builtin_amdgcn_s_barrier();             // B0 stays in flight (no vmcnt drain)
  __builtin_amdgcn_sched_barrier(0);

  // ---- 4 tiles, no barriers (LDS read-only), counted vmcnt on B dbuf ----
#pragma unroll
  for (int t = 0; t < 4; ++t) {
    if (t < 3) loadB(t + 1, (t + 1) & 1);
    if (t < 3) asm volatile("s_waitcnt vmcnt(8)" ::: "memory");
    else       asm volatile("s_waitcnt vmcnt(0)" ::: "memory");
#pragma unroll
    for (int s2 = 0; s2 < 2; ++s2) {
      bf16x8 a[4];
      int cl = s2 * 4 + (lane >> 4);
#pragma unroll
      for (int mf = 0; mf < 4; ++mf) {
        int m = 16 * mf + (lane & 15);
        a[mf] = *(const bf16x8*)&As[t][m * 64 + ((cl ^ (m & 7)) * 8)];
      }
#pragma unroll
      for (int mf = 0; mf < 4; ++mf)
#pragma unroll
        for (int nf = 0; nf < 4; ++nf)
          acc[mf][nf] = __builtin_amdgcn_mfma_f32_16x16x32_bf16(
              a[mf], bv[t & 1][s2 * 4 + nf], acc[mf][nf], 0, 0, 0);
    }
  }

  // ---- epilogue: + Pr[row[e]][n] + Pc[col[e]][n], store ----
#pragma unroll
  for (int mf = 0; mf < 4; ++mf) {
#pragma unroll
    for (int q = 0; q < 4; ++q) {
      long e = e0 + 16 * mf + (lane >> 4) * 4 + q;
      bool ok = e < E;
      long ec = ok ? e : (E - 1);
      int re = ei[ec], ce = ei[(long)E + ec];
      const float* pr = Pr + (long)re * OUT_DIM;
      const float* pc = Pc + (long)ce * OUT_DIM;
      if (ok) {
#pragma unroll
        for (int nf = 0; nf < 4; ++nf) {
          int n = nbase + 16 * nf + (lane & 15);
          outE[e * OUT_DIM + n] = acc[mf][nf][q] + pr[n] + pc[n];
        }
      }
    }
  }
}

extern "C" void kernel_launch(void* const* d_in, const int* in_sizes, int n_in,
                              void* d_out, int out_size, void* d_ws, size_t ws_size,
                              hipStream_t stream) {
  const float* x    = (const float*)d_in[0];
  const int*   ei   = (const int*)d_in[2];
  const float* ea   = (const float*)d_in[3];
  const float* mask = (const float*)d_in[4];
  const float* W    = (const float*)d_in[5];
  const float* b    = (const float*)d_in[6];
  const int E = in_sizes[4];
  const int N = in_sizes[0] / NDIM;

  // ws layout
  char* p = (char*)d_ws;
  int* counts  = (int*)p; p += (long)N * 4;
  int* cursor  = (int*)p; p += (long)N * 4;
  int* offsets = (int*)p; p += (long)(N + 1) * 4;
  int* csr     = (int*)p; p += (long)E * 4;
  p = (char*)(((uintptr_t)p + 15) & ~(uintptr_t)15);
  short* nrepb = (short*)p; p += (long)N * NRP * 2;
  short* Weat  = (short*)p; p += (long)OUT_DIM * 256 * 2;
  short* Wrt   = (short*)p; p += (long)OUT_DIM * NRP * 2;
  short* Wct   = (short*)p; p += (long)OUT_DIM * NRP * 2;
  float* Pr    = (float*)p; p += (long)N * OUT_DIM * 4;
  float* Pc    = (float*)p;

  float* outN = (float*)d_out;
  float* outE = outN + (long)N * NR;

  hipMemsetAsync(counts, 0, (size_t)2 * N * 4, stream);   // counts + cursor

  hist_kernel<<<(E + 255) / 256, 256, 0, stream>>>(ei, counts, E);
  scan_kernel<<<1, SCAN_T, 0, stream>>>(counts, offsets, N);
  scatter_kernel<<<(E + 255) / 256, 256, 0, stream>>>(ei, offsets, cursor, csr, E);
  reduce_kernel<<<(N + 3) / 4, 256, 0, stream>>>(csr, offsets, counts, ea, mask, x,
                                                 outN, nrepb, N);
  int wtot = OUT_DIM * 256 + 2 * OUT_DIM * NRP;
  wprep_kernel<<<(wtot + 255) / 256, 256, 0, stream>>>(W, Weat, Wrt, Wct);
  dim3 pg((N + 63) / 64, 2);
  pgemm_kernel<<<pg, 256, 0, stream>>>(nrepb, Wrt, Wct, b, Pr, Pc, N);
  egemm_kernel<<<(E + 63) / 64, 256, 0, stream>>>(ei, ea, Weat, Pr, Pc, outE, E);
}